// Round 14
// baseline (120.014 us; speedup 1.0000x reference)
//
#include <hip/hip_runtime.h>
#include <stdint.h>
#include <stddef.h>

// MambaMesh random-walk + gather-recenter.  R14: chain/walk pipelining.
// PRNG (bit-exact vs JAX partitionable Threefry, verified R1-R13, absmax 0.0):
//   split(key,n)[j]        = threefry2x32(key; 0, j)   (both output words)
//   random_bits(key,32,()) = xor-fold of threefry2x32(key; 0, 0)
// R13 lessons: (a) the 268MB ws poison fill (~41us) happens EVERY replay
// regardless of ws use -> ~57us fixed bench floor; (b) walk_fast 41us is
// serial-latency: chain(~15us) -> trees -> walk(~10us) run SEQUENTIALLY.
// R14: run them CONCURRENTLY. 1024-thr block: all waves stage nb (~2us);
// then wave0 walks immediately while waves 1-15 redundantly run their own
// carry chains (lanes0-15 = walks) and publish pick-codes for steps
// c === (wave-1) mod 15 as LDS bytes with a ready bit (code|0x80) — 1-word
// message passing, no barriers in the loop; walker spin-reads (volatile).
// Critical path ~= staging + max(walk, code production) ~= 15-18us.

namespace {

__device__ __forceinline__ uint32_t rotl32(uint32_t x, int r) {
  return (x << r) | (x >> (32 - r));
}

// Threefry-2x32, 20 rounds — exactly JAX's threefry2x32_p.
__device__ __forceinline__ void tf2x32(uint32_t ka, uint32_t kb,
                                       uint32_t x0, uint32_t x1,
                                       uint32_t& o0, uint32_t& o1) {
  const uint32_t kc = ka ^ kb ^ 0x1BD11BDAu;
  x0 += ka; x1 += kb;
#define TF_R4(r0, r1, r2, r3)                          \
  x0 += x1; x1 = rotl32(x1, r0); x1 ^= x0;             \
  x0 += x1; x1 = rotl32(x1, r1); x1 ^= x0;             \
  x0 += x1; x1 = rotl32(x1, r2); x1 ^= x0;             \
  x0 += x1; x1 = rotl32(x1, r3); x1 ^= x0;
  TF_R4(13, 15, 26, 6)  x0 += kb; x1 += kc + 1u;
  TF_R4(17, 29, 16, 24) x0 += kc; x1 += ka + 2u;
  TF_R4(13, 15, 26, 6)  x0 += ka; x1 += kb + 3u;
  TF_R4(17, 29, 16, 24) x0 += kb; x1 += kc + 4u;
  TF_R4(13, 15, 26, 6)  x0 += kc; x1 += ka + 5u;
#undef TF_R4
  o0 = x0; o1 = x1;
}

__device__ __forceinline__ void randbits(uint32_t ka, uint32_t kb,
                                         uint32_t& hi, uint32_t& lo) {
  uint32_t s0a, s0b, s1a, s1b, h0, h1;
  tf2x32(ka, kb, 0u, 0u, s0a, s0b);
  tf2x32(ka, kb, 0u, 1u, s1a, s1b);
  tf2x32(s0a, s0b, 0u, 0u, h0, h1);
  hi = h0 ^ h1;
  tf2x32(s1a, s1b, 0u, 0u, h0, h1);
  lo = h0 ^ h1;
}

__device__ __forceinline__ uint32_t r_generic(uint32_t hi, uint32_t lo,
                                              uint32_t span) {
  uint32_t mult = 65536u % span;
  mult = (mult * mult) % span;
  return ((hi % span) * mult + (lo % span)) % span;
}

// pick code: r3 (span=3 result) in bits 0..1, r2 (span=2 result) in bit 2.
__device__ __forceinline__ uint32_t pick_code(uint32_t hi, uint32_t lo) {
  return ((hi % 3u + lo % 3u) % 3u) | ((lo & 1u) << 2);
}

// k_idx recomputed from k0 — RARE paths only (bit-exact).
__device__ __noinline__ void live_key(int w, int idx, uint32_t& ka,
                                      uint32_t& kb) {
  tf2x32(0u, 42u, 0u, (uint32_t)w, ka, kb);
  for (int c = 0; c < idx; ++c) tf2x32(ka, kb, 0u, 0u, ka, kb);
}

constexpr int CH = 64;          // code steps (covers seq_len 63)
constexpr int WPB = 16;         // walks per block
constexpr int NMAXF = 20000;    // fast-path row capacity
constexpr int BMWF = 625;       // bitmap words per walk (20,000 bits)
constexpr int SEQSF = 64;       // seqL stride (u16)
constexpr int NTHR = 1024;      // fast-kernel block size (16 waves)
constexpr int KSTRIDE = 65;     // fallback keys stride
constexpr int VISW = 2048;      // fallback bitmap words (N <= 65536)
constexpr int NMAX = 20032;     // legacy fast-guard bound for walk_any skip

// =================== FAST kernel: pipelined, ws-free ======================
__global__ __launch_bounds__(NTHR) void walk_fast(
    const float* __restrict__ xyz, const int* __restrict__ nbrs,
    const int* __restrict__ centers, const int* __restrict__ n_faces_p,
    const int* __restrict__ seq_len_p, float* __restrict__ out,
    int s0, int num_walks, int Lp1) {
  __shared__ uint32_t nb01L[NMAXF];        // 80,000 B  n0 | n1<<16
  __shared__ uint16_t nb2L[NMAXF];         // 40,000 B  n2
  __shared__ uint32_t visL[WPB * BMWF];    // 40,000 B  bitmaps
  __shared__ uint16_t seqL[WPB * SEQSF];   //  2,048 B
  __shared__ uint8_t  codesL[WPB * CH];    //  1,024 B  code|0x80 ready flag
                                           // total 163,072 B

  const int tid = threadIdx.x, lane = tid & 63, wv = tid >> 6;
  const int w0 = blockIdx.x * WPB;
  if (w0 >= num_walks) return;
  const int N = *n_faces_p, L = *seq_len_p;
  const int B = s0 / (3 * N), G = num_walks / B;
  const bool fast = (N <= NMAXF) && (L <= 63) && (G % WPB == 0);
  if (!fast) return;                       // fallback kernel handles it

  const int b = w0 / G;                    // uniform batch (G%16==0)
  const int* __restrict__ nbs  = nbrs + (size_t)b * N * 3;
  const float* __restrict__ xb = xyz + (size_t)b * N * 3;

  // Walker's centers read issued at kernel top (hidden under staging).
  int f0 = 0;
  const bool walk_lane = (wv == 0) && (lane < WPB) && (w0 + lane < num_walks);
  if (walk_lane) f0 = centers[w0 + lane];

  // ---- Phase A: ALL 16 waves stage table + clear state (fast) ------------
  for (int r = tid; r < N; r += NTHR) {
    const int3 v = *reinterpret_cast<const int3*>(nbs + 3 * (size_t)r);
    nb01L[r] = (uint32_t)v.x | ((uint32_t)v.y << 16);
    nb2L[r]  = (uint16_t)v.z;
  }
  for (int j = tid; j < WPB * BMWF; j += NTHR) visL[j] = 0u;
  codesL[tid < WPB * CH ? tid : 0] = 0u;   // WPB*CH == 1024 == NTHR
  __syncthreads();

  if (wv == 0) {
    // =================== WALKER (16 walks on lanes 0-15) ==================
    const int wl = lane;
    const int wg = w0 + wl;
    const bool alive = walk_lane;
    volatile uint8_t* __restrict__ codesV = codesL;

    int n0 = 0, n1 = 0, n2 = 0, i = 1, bs = 1, cstep = 0;
    if (alive) {
      seqL[wl * SEQSF + 0] = (uint16_t)f0;
      visL[wl * BMWF + ((unsigned)f0 >> 5)] = 1u << (f0 & 31);
      const uint32_t p = nb01L[f0];
      n0 = (int)(p & 0xffffu); n1 = (int)(p >> 16); n2 = (int)nb2L[f0];
    }
    for (;;) {
      const bool go = alive && (i <= L);
      if (!__ballot(go)) break;
      if (go) {
        const int idx = cstep; ++cstep;
        const uint32_t wa = visL[wl * BMWF + ((unsigned)n0 >> 5)];
        const uint32_t wb = visL[wl * BMWF + ((unsigned)n1 >> 5)];
        const uint32_t wc = visL[wl * BMWF + ((unsigned)n2 >> 5)];
        const uint32_t pA = nb01L[n0]; const uint32_t a2 = nb2L[n0];
        const uint32_t pB = nb01L[n1]; const uint32_t b2 = nb2L[n1];
        const uint32_t pC = nb01L[n2]; const uint32_t c2 = nb2L[n2];
        const uint32_t u0 = ((wa >> (n0 & 31)) & 1u) ^ 1u;
        const uint32_t u1 = ((wb >> (n1 & 31)) & 1u) ^ 1u;
        const uint32_t u2 = ((wc >> (n2 & 31)) & 1u) ^ 1u;
        const uint32_t cnt = u0 + u1 + u2;

        int to_add, sel;
        if (__builtin_expect(cnt == 0, 0)) {
          // ---- rare backtrack (per-lane, live hashing, bit-exact) ----
          sel = -1;
          uint32_t kia, kib;
          live_key(wg, idx, kia, kib);
          uint32_t kka, kkb;
          tf2x32(kia, kib, 0u, 2u, kka, kkb);  // k2
          bool found = false;
          int ta = 0, bsc = bs;
          while (!found && i > bsc) {
            uint32_t ca, cb, kpa, kpb;
            tf2x32(kka, kkb, 0u, 0u, ca, cb);
            tf2x32(kka, kkb, 0u, 1u, kpa, kpb);
            const int back = (int)seqL[wl * SEQSF + (i - bsc - 1)];
            const uint32_t pm = nb01L[back];
            const int m0 = (int)(pm & 0xffffu), m1 = (int)(pm >> 16);
            const int m2 = (int)nb2L[back];
            const uint32_t e0 =
                ((visL[wl * BMWF + (m0 >> 5)] >> (m0 & 31)) & 1u) ^ 1u;
            const uint32_t e1 =
                ((visL[wl * BMWF + (m1 >> 5)] >> (m1 & 31)) & 1u) ^ 1u;
            const uint32_t e2 =
                ((visL[wl * BMWF + (m2 >> 5)] >> (m2 & 31)) & 1u) ^ 1u;
            const uint32_t bc = e0 + e1 + e2;
            if (bc > 0) {
              uint32_t bhi, blo;
              randbits(kpa, kpb, bhi, blo);
              const uint32_t bcode = pick_code(bhi, blo);
              const uint32_t r3 = bcode & 3u, r2 = (bcode >> 2) & 1u;
              const uint32_t t2v = (bc == 3 ? r3 : (bc == 2 ? r2 : 0)) + 1;
              ta = (e0 == t2v) ? m0 : ((e0 + e1 == t2v) ? m1 : m2);
              found = true;
            } else {
              bsc += 2;
            }
            kka = ca; kkb = cb;
          }
          if (found) {
            const int i_new = i - bsc;
            for (int a = i_new; a < i; ++a)
              seqL[wl * SEQSF + a] = (uint16_t)ta;   // ref's seq-splat
            to_add = ta; bs = bsc; i = i_new;
          } else {
            uint32_t k3a, k3b, rh, rl;
            tf2x32(kia, kib, 0u, 3u, k3a, k3b);      // k3
            randbits(k3a, k3b, rh, rl);
            to_add = (int)r_generic(rh, rl, (uint32_t)N);
            bs = 1;
          }
        } else {
          // ---- common path: poll the pipelined code byte ----
          uint32_t code;
          if (__builtin_expect(idx >= CH, 0)) {      // beyond produced steps
            uint32_t ia, ib, k1a, k1b, h2, l2;
            live_key(wg, idx, ia, ib);
            tf2x32(ia, ib, 0u, 1u, k1a, k1b);
            randbits(k1a, k1b, h2, l2);
            code = pick_code(h2, l2);
          } else {
            uint8_t bv = codesV[(wl << 6) | idx];
            while (!(bv & 0x80u)) bv = codesV[(wl << 6) | idx];  // spin
            code = bv & 0x7fu;
          }
          const uint32_t r3 = code & 3u, r2 = (code >> 2) & 1u;
          const uint32_t target = (cnt == 3 ? r3 : (cnt == 2 ? r2 : 0)) + 1;
          sel = (u0 == target) ? 0 : ((u0 + u1 == target) ? 1 : 2);
          to_add = (sel == 0) ? n0 : ((sel == 1) ? n1 : n2);
          bs = 1;
        }
        // ---- common tail ----
        const unsigned word = wl * BMWF + ((unsigned)to_add >> 5);
        visL[word] = visL[word] | (1u << (to_add & 31));
        seqL[wl * SEQSF + i] = (uint16_t)to_add;
        ++i;
        if (sel == 0)      { n0 = (int)(pA & 0xffffu); n1 = (int)(pA >> 16); n2 = (int)a2; }
        else if (sel == 1) { n0 = (int)(pB & 0xffffu); n1 = (int)(pB >> 16); n2 = (int)b2; }
        else if (sel == 2) { n0 = (int)(pC & 0xffffu); n1 = (int)(pC >> 16); n2 = (int)c2; }
        else {
          const uint32_t p = nb01L[to_add];
          n0 = (int)(p & 0xffffu); n1 = (int)(p >> 16); n2 = (int)nb2L[to_add];
        }
      }
    }
  } else {
    // ============ CODE PRODUCERS: waves 1-15, lanes 0-15 = walks ==========
    if (lane < WPB) {
      const int wg = w0 + lane;            // chain valid for any wg (unused
      uint32_t ka, kb;                     // codes simply never read)
      tf2x32(0u, 42u, 0u, (uint32_t)wg, ka, kb);   // k_0
      const int phase = wv - 1;            // 0..14
#pragma clang loop unroll(disable)
      for (int c2 = 0; c2 < CH; ++c2) {
        if (c2 % 15 == phase) {
          uint32_t k1a, k1b, hi, lo;
          tf2x32(ka, kb, 0u, 1u, k1a, k1b);        // k1 = split(k,4)[1]
          randbits(k1a, k1b, hi, lo);
          codesL[(lane << 6) | c2] = (uint8_t)(pick_code(hi, lo) | 0x80u);
        }
        tf2x32(ka, kb, 0u, 0u, ka, kb);            // advance chain
      }
    }
  }
  __syncthreads();

  // ---- Phase D: gather + recenter straight from seqL (all 1024 thr) -----
  for (int idx = tid; idx < WPB * Lp1; idx += NTHR) {
    const int wl = idx / Lp1, t = idx - wl * Lp1;
    const int wg = w0 + wl;
    if (wg < num_walks) {
      const int node = (int)seqL[wl * SEQSF + t];
      const int c0 = centers[wg];
      float3 v;
      v.x = xb[3 * (size_t)node + 0] - xb[3 * (size_t)c0 + 0];
      v.y = xb[3 * (size_t)node + 1] - xb[3 * (size_t)c0 + 1];
      v.z = xb[3 * (size_t)node + 2] - xb[3 * (size_t)c0 + 2];
      *reinterpret_cast<float3*>(out + ((size_t)wg * Lp1 + t) * 3) = v;
    }
  }
}

// ============ FALLBACK kernel: any shape (R10-verified), ws-free ==========
__global__ __launch_bounds__(1024) void walk_any(
    const float* __restrict__ xyz, const int* __restrict__ nbrs,
    const int* __restrict__ centers, const int* __restrict__ n_faces_p,
    const int* __restrict__ seq_len_p, float* __restrict__ out,
    int s0, int num_walks, int Lp1) {
  __shared__ uint32_t visL[WPB * VISW];
  __shared__ uint2 keysL[WPB * KSTRIDE];

  const int tid = threadIdx.x;
  const int wv = tid >> 6, lane = tid & 63;
  const int w0 = blockIdx.x * WPB;
  if (w0 >= num_walks) return;
  const int N = *n_faces_p, L = *seq_len_p;
  const int B = s0 / (3 * N), G = num_walks / B;
  if ((N <= NMAXF) && (L <= 63) && (G % WPB == 0)) return;  // fast handled
  const int w = w0 + wv;
  const bool active = (w < num_walks);
  const bool bm_ok = (N <= VISW * 32);

  const int bb = (active ? w : w0) / G;
  const int* __restrict__ nb   = nbrs + (size_t)bb * N * 3;
  const float* __restrict__ xb = xyz + (size_t)bb * N * 3;

  const int f0 = active ? centers[w] : 0;
  int3 row = active ? *reinterpret_cast<const int3*>(nb + 3 * (size_t)f0)
                    : make_int3(0, 0, 0);

  uint32_t* __restrict__ visW = visL + wv * VISW;
  if (bm_ok) {
    for (int j = lane; j < VISW; j += 64) visW[j] = 0u;
    if (lane == 0 && active) visW[(unsigned)f0 >> 5] = 1u << (f0 & 31);
  }
  if (wv == 0 && lane < WPB && (w0 + lane) < num_walks) {
    uint32_t ka, kb;
    tf2x32(0u, 42u, 0u, (uint32_t)(w0 + lane), ka, kb);
    keysL[lane * KSTRIDE + 0] = make_uint2(ka, kb);
#pragma clang loop unroll(disable)
    for (int c2 = 1; c2 < CH; ++c2) {
      tf2x32(ka, kb, 0u, 0u, ka, kb);
      keysL[lane * KSTRIDE + c2] = make_uint2(ka, kb);
    }
  }
  __syncthreads();
  if (!active) return;

  const uint2 mykey = keysL[wv * KSTRIDE + lane];
  uint32_t mycode;
  {
    uint32_t k1a, k1b, hi, lo;
    tf2x32(mykey.x, mykey.y, 0u, 1u, k1a, k1b);
    randbits(k1a, k1b, hi, lo);
    mycode = pick_code(hi, lo);
  }
  uint32_t extka = 0, extkb = 0;
  int extc = -1;
  auto get_key = [&](int idx, uint32_t& ra, uint32_t& rb) {
    if (idx < CH) {
      ra = (uint32_t)__shfl((int)mykey.x, idx);
      rb = (uint32_t)__shfl((int)mykey.y, idx);
    } else {
      if (extc < 0) {
        extka = (uint32_t)__shfl((int)mykey.x, CH - 1);
        extkb = (uint32_t)__shfl((int)mykey.y, CH - 1);
        extc = CH - 1;
      }
      while (extc < idx) { tf2x32(extka, extkb, 0u, 0u, extka, extkb); ++extc; }
      ra = extka; rb = extkb;
    }
  };

  int seqr = (lane == 0) ? f0 : -1;
  int i = 1, bs = 1, c = 0;
  int hist = (lane == 0) ? f0 : -1, hist2 = -1;

  while (i <= L) {
    const int idx = c; ++c;
    const bool deep = (idx >= CH);
    const int n0 = row.x, n1 = row.y, n2 = row.z;
    uint32_t u0, u1, u2;
    if (bm_ok) {
      u0 = ((visW[(unsigned)n0 >> 5] >> (n0 & 31)) & 1u) ^ 1u;
      u1 = ((visW[(unsigned)n1 >> 5] >> (n1 & 31)) & 1u) ^ 1u;
      u2 = ((visW[(unsigned)n2 >> 5] >> (n2 & 31)) & 1u) ^ 1u;
    } else {
      int v0 = __any(hist == n0), v1 = __any(hist == n1), v2 = __any(hist == n2);
      if (deep) {
        v0 |= __any(hist2 == n0); v1 |= __any(hist2 == n1); v2 |= __any(hist2 == n2);
      }
      u0 = 1 - v0; u1 = 1 - v1; u2 = 1 - v2;
    }
    const uint32_t cnt = u0 + u1 + u2;

    int to_add;
    bool hit = false;
    int bsf = bs;
    if (cnt > 0) {
      uint32_t code;
      if (deep) {
        uint32_t ia, ib, k1a, k1b, hi, lo;
        get_key(idx, ia, ib);
        tf2x32(ia, ib, 0u, 1u, k1a, k1b);
        randbits(k1a, k1b, hi, lo);
        code = pick_code(hi, lo);
      } else {
        code = (uint32_t)__builtin_amdgcn_readlane((int)mycode, idx);
      }
      const uint32_t r3 = code & 3u, r2 = (code >> 2) & 1u;
      const uint32_t target = (cnt == 3 ? r3 : (cnt == 2 ? r2 : 0)) + 1;
      to_add = (u0 == target) ? n0 : ((u0 + u1 == target) ? n1 : n2);
    } else {
      uint32_t kia, kib;
      get_key(idx, kia, kib);
      uint32_t kka, kkb;
      tf2x32(kia, kib, 0u, 2u, kka, kkb);
      bool found = false;
      int ta = 0, bsc = bs;
      while (!found && i > bsc) {
        uint32_t ca, cb, kpa, kpb;
        tf2x32(kka, kkb, 0u, 0u, ca, cb);
        tf2x32(kka, kkb, 0u, 1u, kpa, kpb);
        const int back = __shfl(seqr, i - bsc - 1);
        const int3 br = *reinterpret_cast<const int3*>(nb + 3 * (size_t)back);
        uint32_t e0, e1, e2;
        if (bm_ok) {
          e0 = ((visW[(unsigned)br.x >> 5] >> (br.x & 31)) & 1u) ^ 1u;
          e1 = ((visW[(unsigned)br.y >> 5] >> (br.y & 31)) & 1u) ^ 1u;
          e2 = ((visW[(unsigned)br.z >> 5] >> (br.z & 31)) & 1u) ^ 1u;
        } else {
          int a0 = __any(hist == br.x), a1 = __any(hist == br.y), a2m = __any(hist == br.z);
          if (deep) {
            a0 |= __any(hist2 == br.x); a1 |= __any(hist2 == br.y); a2m |= __any(hist2 == br.z);
          }
          e0 = 1 - a0; e1 = 1 - a1; e2 = 1 - a2m;
        }
        const uint32_t bc = e0 + e1 + e2;
        if (bc > 0) {
          uint32_t bhi, blo;
          randbits(kpa, kpb, bhi, blo);
          const uint32_t bcode = pick_code(bhi, blo);
          const uint32_t r3 = bcode & 3u, r2 = (bcode >> 2) & 1u;
          const uint32_t t2v = (bc == 3 ? r3 : (bc == 2 ? r2 : 0)) + 1;
          ta = (e0 == t2v) ? br.x : ((e0 + e1 == t2v) ? br.y : br.z);
          found = true;
        } else {
          bsc += 2;
        }
        kka = ca; kkb = cb;
      }
      if (found) {
        to_add = ta; hit = true; bsf = bsc;
      } else {
        uint32_t k3a, k3b, rh, rl;
        tf2x32(kia, kib, 0u, 3u, k3a, k3b);
        randbits(k3a, k3b, rh, rl);
        to_add = (int)r_generic(rh, rl, (uint32_t)N);
      }
    }

    int i_new, up;
    if (hit) { i_new = i - bsf; bs = bsf; up = i - 1; }
    else     { i_new = i;       bs = 1;   up = i; }
    seqr = (lane >= i_new && lane <= up) ? to_add : seqr;
    if (bm_ok) {
      if (lane == 0) {
        const unsigned word = (unsigned)to_add >> 5;
        visW[word] |= 1u << (to_add & 31);
      }
    } else {
      const int slot = idx + 1;
      if (slot < CH)          hist  = (lane == slot)      ? to_add : hist;
      else if (slot < 2 * CH) hist2 = (lane == slot - CH) ? to_add : hist2;
    }
    i = i_new + 1;
    row = *reinterpret_cast<const int3*>(nb + 3 * (size_t)to_add);
  }

  const float cx = xb[3 * (size_t)f0 + 0];
  const float cy = xb[3 * (size_t)f0 + 1];
  const float cz = xb[3 * (size_t)f0 + 2];
  if (lane < Lp1) {
    const int node = seqr;
    float3 v;
    v.x = xb[3 * (size_t)node + 0] - cx;
    v.y = xb[3 * (size_t)node + 1] - cy;
    v.z = xb[3 * (size_t)node + 2] - cz;
    *reinterpret_cast<float3*>(out + ((size_t)w * Lp1 + lane) * 3) = v;
  }
}

}  // namespace

extern "C" void kernel_launch(void* const* d_in, const int* in_sizes, int n_in,
                              void* d_out, int out_size, void* d_ws, size_t ws_size,
                              hipStream_t stream) {
  const float* xyz     = (const float*)d_in[0];
  const int*   nbrs    = (const int*)d_in[1];
  const int*   centers = (const int*)d_in[2];
  const int*   n_faces = (const int*)d_in[3];
  const int*   seq_len = (const int*)d_in[4];
  float* out = (float*)d_out;

  const int s0 = in_sizes[0];                  // B*N*3
  const int num_walks = in_sizes[2];           // B*G
  const int Lp1 = out_size / (3 * num_walks);  // seq_len+1

  const int blocks = (num_walks + WPB - 1) / WPB;
  // Exactly one of these does the work (grid-uniform shape test); the other
  // exits in ~2us. No d_ws use (the harness ws-poison fill happens anyway,
  // but reading poisoned ws would be incorrect and writing it buys nothing).
  walk_fast<<<blocks, NTHR, 0, stream>>>(
      xyz, nbrs, centers, n_faces, seq_len, out, s0, num_walks, Lp1);
  walk_any<<<blocks, WPB * 64, 0, stream>>>(
      xyz, nbrs, centers, n_faces, seq_len, out, s0, num_walks, Lp1);
}